// Round 1
// baseline (722.660 us; speedup 1.0000x reference)
//
#include <hip/hip_runtime.h>

// DGCN decomposition:
//   m = MLP(x[0])                       (tiny, fp32)
//   S = softmax(relu(E1 @ m @ E2^T))    (row softmax, fp32 -> bf16)
//   G1 = S @ X, G2 = S @ G1             (bf16 MFMA GEMMs, X = x as [m, (b,i,s)])
//   out[b,o,n,s] = bias[n,o] + sum_{k,i} Gk[n,(b,i,s)] * W[n,k,i,o]
// S^2 is never materialized (saves a 2048^3 GEMM).

typedef float  f32x4  __attribute__((ext_vector_type(4)));
typedef __bf16 bf16x8 __attribute__((ext_vector_type(8)));

#define GLOAD16(gp, lp) __builtin_amdgcn_global_load_lds( \
    (const __attribute__((address_space(1))) void*)(gp),  \
    (__attribute__((address_space(3))) void*)(lp), 16, 0, 0)

__device__ __forceinline__ unsigned short f2bf(float f){
  union { float f; unsigned u; } v; v.f = f;
  unsigned u = v.u;
  u += 0x7fffu + ((u >> 16) & 1u);   // round-to-nearest-even
  return (unsigned short)(u >> 16);
}
__device__ __forceinline__ float bf2f(unsigned short h){
  union { unsigned u; float f; } v; v.u = ((unsigned)h) << 16;
  return v.f;
}

// ---------------- K1: h1[i,n] = tanh(x[0,i,n,:] . fc0_w + fc0_b) ----------------
__global__ void k_h1(const float* __restrict__ x, const float* __restrict__ fc0w,
                     const float* __restrict__ fc0b, float* __restrict__ h1){
  int g = blockIdx.x * 256 + threadIdx.x;        // g = i*2048 + n, 65536 total
  const float* xp = x + (long)g * 12;
  float s = fc0b[0];
  #pragma unroll
  for (int j = 0; j < 12; j++) s += xp[j] * fc0w[j];
  h1[g] = tanhf(s);
}

// ---------------- K2a: h2raw[i*16+d] = sum_n h1[i,n]*fc1_w[d,n] ----------------
__global__ __launch_bounds__(256) void k_h2a(const float* __restrict__ h1,
                                             const float* __restrict__ fc1w,
                                             float* __restrict__ h2raw){
  __shared__ float red[4];
  int id = blockIdx.x;                 // 0..511 = i*16+d
  int i = id >> 4, d = id & 15;
  int t = threadIdx.x;
  const float* hp = h1 + i * 2048;
  const float* wp = fc1w + d * 2048;
  float s = 0.f;
  for (int nn = t; nn < 2048; nn += 256) s += hp[nn] * wp[nn];
  for (int off = 32; off > 0; off >>= 1) s += __shfl_down(s, off, 64);
  if ((t & 63) == 0) red[t >> 6] = s;
  __syncthreads();
  if (t == 0) h2raw[id] = red[0] + red[1] + red[2] + red[3];
}

// ---------------- K2b: h2 = tanh(h2raw + fc1_b); m[d,e] = tanh(sum_i h2[i,d]*fc2_w[e,i] + fc2_b[e]) ----------------
__global__ void k_h2b(const float* __restrict__ h2raw, const float* __restrict__ fc1b,
                      const float* __restrict__ fc2w, const float* __restrict__ fc2b,
                      float* __restrict__ mmat){
  __shared__ float h2[512];
  int t = threadIdx.x;                 // 512 threads
  {
    int d = t & 15;
    h2[t] = tanhf(h2raw[t] + fc1b[d]);
  }
  __syncthreads();
  if (t < 256){
    int dd = t >> 4, e = t & 15;
    float s2 = fc2b[e];
    #pragma unroll
    for (int ii = 0; ii < 32; ii++) s2 += h2[ii * 16 + dd] * fc2w[e * 32 + ii];
    mmat[dd * 16 + e] = tanhf(s2);
  }
}

// ---------------- K3: support row n = softmax_j(relu(sum_d' (E1[n]@m)[d'] * E2[j,d'])) -> bf16 ----------------
__global__ __launch_bounds__(256) void k_support(const float* __restrict__ E1,
                                                 const float* __restrict__ E2,
                                                 const float* __restrict__ mmat,
                                                 unsigned short* __restrict__ sup){
  __shared__ float ml[256];
  __shared__ float tv[16];
  __shared__ float red[8];
  int n = blockIdx.x, t = threadIdx.x;
  ml[t] = mmat[t];
  __syncthreads();
  if (t < 16){
    float s = 0.f;
    const float* er = E1 + n * 16;
    #pragma unroll
    for (int d = 0; d < 16; d++) s += er[d] * ml[d * 16 + t];
    tv[t] = s;
  }
  __syncthreads();
  float lmax = -1e30f;
  float lv[8];
  #pragma unroll
  for (int p = 0; p < 8; p++){
    int j = t + p * 256;
    const float* e2 = E2 + j * 16;
    float s = 0.f;
    #pragma unroll
    for (int d = 0; d < 16; d++) s += tv[d] * e2[d];
    s = fmaxf(s, 0.f);                 // relu BEFORE softmax
    lv[p] = s;
    lmax = fmaxf(lmax, s);
  }
  for (int off = 32; off > 0; off >>= 1) lmax = fmaxf(lmax, __shfl_down(lmax, off, 64));
  if ((t & 63) == 0) red[t >> 6] = lmax;
  __syncthreads();
  if (t == 0) red[0] = fmaxf(fmaxf(red[0], red[1]), fmaxf(red[2], red[3]));
  __syncthreads();
  float mx = red[0];
  float lsum = 0.f;
  #pragma unroll
  for (int p = 0; p < 8; p++){ float e = __expf(lv[p] - mx); lv[p] = e; lsum += e; }
  for (int off = 32; off > 0; off >>= 1) lsum += __shfl_down(lsum, off, 64);
  if ((t & 63) == 0) red[4 + (t >> 6)] = lsum;
  __syncthreads();
  if (t == 0) red[4] = red[4] + red[5] + red[6] + red[7];
  __syncthreads();
  float inv = 1.f / red[4];
  #pragma unroll
  for (int p = 0; p < 8; p++) sup[(long)n * 2048 + t + p * 256] = f2bf(lv[p] * inv);
}

// ---------------- K4a: Xb[m][c] = bf16(x[b,i,m,s]), c=(b*32+i)*12+s ----------------
__global__ void k_xb(const float* __restrict__ x, unsigned short* __restrict__ Xb){
  int idx = blockIdx.x * 256 + threadIdx.x;      // < 2048*12288
  int m = idx / 12288;
  int c = idx - m * 12288;
  int bi = c / 12, s = c - bi * 12;
  Xb[idx] = f2bf(x[((long)bi * 2048 + m) * 12 + s]);
}

// ---------------- K4b: Xbt[c][m] = Xb[m][c]  (64x64 LDS tile transpose) ----------------
__global__ __launch_bounds__(256) void k_xbt(const unsigned short* __restrict__ Xb,
                                             unsigned short* __restrict__ Xbt){
  __shared__ unsigned short tile[64][65];
  int cT = blockIdx.x * 64;            // 192 tiles over 12288
  int mT = blockIdx.y * 64;            // 32 tiles over 2048
  int t = threadIdx.x;
  int r = t >> 6, cc = t & 63;
  #pragma unroll
  for (int p = 0; p < 16; p++){
    int rr = p * 4 + r;
    tile[rr][cc] = Xb[(long)(mT + rr) * 12288 + cT + cc];
  }
  __syncthreads();
  #pragma unroll
  for (int p = 0; p < 16; p++){
    int rr = p * 4 + r;
    Xbt[(long)(cT + rr) * 2048 + mT + cc] = tile[cc][rr];
  }
}

// ---------------- K6: W[n,k,i,o] = sum_d E1[n,d]P1[d,k,i,o] + E2[n,d]P2[d,k,i,o]; bias likewise ----------------
__global__ void k_wb(const float* __restrict__ E1, const float* __restrict__ E2,
                     const float* __restrict__ P1, const float* __restrict__ P2,
                     const float* __restrict__ BP1, const float* __restrict__ BP2,
                     float* __restrict__ W, float* __restrict__ biasN){
  long g = (long)blockIdx.x * 256 + threadIdx.x;
  const long NW = (long)2048 * 3072;
  if (g < NW){
    int n = (int)(g / 3072), r = (int)(g - (long)n * 3072);
    const float* e1 = E1 + n * 16; const float* e2 = E2 + n * 16;
    float s = 0.f;
    #pragma unroll
    for (int d = 0; d < 16; d++) s += e1[d] * P1[d * 3072 + r] + e2[d] * P2[d * 3072 + r];
    W[g] = s;
  } else {
    long e = g - NW;
    if (e < 2048 * 32){
      int n = (int)(e >> 5), o = (int)(e & 31);
      const float* e1 = E1 + n * 16; const float* e2 = E2 + n * 16;
      float s = 0.f;
      #pragma unroll
      for (int d = 0; d < 16; d++) s += e1[d] * BP1[d * 32 + o] + e2[d] * BP2[d * 32 + o];
      biasN[e] = s;
    }
  }
}

// ---------------- GEMM: C[m][c] = sum_k A[m][k] * Bt[c][k]; optional C^T output ----------------
// m97 structure: 128x128 tile, BK=32, mfma_f32_16x16x32_bf16, global_load_lds width 16.
__global__ __launch_bounds__(256) void k_gemm(const unsigned short* __restrict__ A,
                                              const unsigned short* __restrict__ Bt,
                                              unsigned short* __restrict__ Cd,
                                              unsigned short* __restrict__ Ct,
                                              int writeT){
  __shared__ unsigned short As[128 * 32];
  __shared__ unsigned short Bs[128 * 32];
  int tid  = threadIdx.x;
  int wave = tid >> 6, lane = tid & 63;
  int l15 = lane & 15, q = lane >> 4;
  int wm = wave >> 1, wc = wave & 1;
  long mBase = (long)blockIdx.y * 128;
  long cBase = (long)blockIdx.x * 128;
  f32x4 acc[4][4];
  #pragma unroll
  for (int t = 0; t < 4; t++)
    #pragma unroll
    for (int u = 0; u < 4; u++) acc[t][u] = (f32x4){0.f, 0.f, 0.f, 0.f};

  // staging: lane -> row = wave*16 + lane/4, 16B chunk = (lane&3)*8 elems
  // LDS dest is wave-uniform base + lane*16B (global_load_lds constraint): holds since
  // lds elem offset = wave*512 + lane*8.
  const unsigned short* gA = A  + (mBase + wave * 16 + (lane >> 2)) * 2048 + (lane & 3) * 8;
  const unsigned short* gB = Bt + (cBase + wave * 16 + (lane >> 2)) * 2048 + (lane & 3) * 8;
  unsigned short* lA0 = As + wave * 512;
  unsigned short* lA1 = As + 2048 + wave * 512;
  unsigned short* lB0 = Bs + wave * 512;
  unsigned short* lB1 = Bs + 2048 + wave * 512;

  for (int k0 = 0; k0 < 2048; k0 += 32){
    __syncthreads();
    GLOAD16(gA + k0,              lA0);
    GLOAD16(gA + 64 * 2048 + k0,  lA1);
    GLOAD16(gB + k0,              lB0);
    GLOAD16(gB + 64 * 2048 + k0,  lB1);
    __syncthreads();               // barrier drains vmcnt -> LDS visible
    bf16x8 a[4], b[4];
    #pragma unroll
    for (int t = 0; t < 4; t++)
      a[t] = *(const bf16x8*)&As[(wm * 64 + t * 16 + l15) * 32 + q * 8];
    #pragma unroll
    for (int u = 0; u < 4; u++)
      b[u] = *(const bf16x8*)&Bs[(wc * 64 + u * 16 + l15) * 32 + q * 8];
    #pragma unroll
    for (int t = 0; t < 4; t++)
      #pragma unroll
      for (int u = 0; u < 4; u++)
        acc[t][u] = __builtin_amdgcn_mfma_f32_16x16x32_bf16(a[t], b[u], acc[t][u], 0, 0, 0);
  }
  // epilogue: D lane map col=l15, row=q*4+reg (verified layout)
  #pragma unroll
  for (int t = 0; t < 4; t++){
    int mloc = wm * 64 + t * 16 + q * 4;
    #pragma unroll
    for (int u = 0; u < 4; u++){
      int cloc = wc * 64 + u * 16 + l15;
      long cg = cBase + cloc;
      long mg = mBase + mloc;
      unsigned short h0 = f2bf(acc[t][u][0]);
      unsigned short h1v = f2bf(acc[t][u][1]);
      unsigned short h2v = f2bf(acc[t][u][2]);
      unsigned short h3v = f2bf(acc[t][u][3]);
      Cd[(mg + 0) * 12288 + cg] = h0;
      Cd[(mg + 1) * 12288 + cg] = h1v;
      Cd[(mg + 2) * 12288 + cg] = h2v;
      Cd[(mg + 3) * 12288 + cg] = h3v;
      if (writeT){
        ushort4 v = make_ushort4(h0, h1v, h2v, h3v);
        *(ushort4*)&Ct[cg * 2048 + mg] = v;
      }
    }
  }
}

// ---------------- K7: out[b,o,n,s] = bias[n,o] + sum_{k,i} Gk[n,(b,i,s)]*W[n,k,i,o] ----------------
__global__ __launch_bounds__(256) void k_final(const unsigned short* __restrict__ G0,
                                               const unsigned short* __restrict__ G1,
                                               const unsigned short* __restrict__ G2,
                                               const float* __restrict__ W,
                                               const float* __restrict__ biasN,
                                               float* __restrict__ out){
  __shared__ float gbuf[12416];   // per-b stride 388 floats (pad 4) -> conflict-free b128 reads
  __shared__ float wbuf[1024];    // W[n][k] slice [i][o]
  __shared__ float bbuf[32];
  int bid = blockIdx.x;
  int n = (bid & 7) * 256 + (bid >> 3);   // XCD-swizzle: adjacent n share an XCD L2 (merge partial lines)
  int t = threadIdx.x;
  int b = t >> 3, oc = t & 7;
  f32x4 accv[4][3];
  #pragma unroll
  for (int jo = 0; jo < 4; jo++)
    #pragma unroll
    for (int v = 0; v < 3; v++) accv[jo][v] = (f32x4){0.f, 0.f, 0.f, 0.f};

  const unsigned short* srcs[3] = {G0, G1, G2};
  for (int k = 0; k < 3; k++){
    __syncthreads();
    const unsigned short* src = srcs[k] + (long)n * 12288;
    for (int e = t; e < 12288; e += 256){
      int bb = e / 384, rr = e - bb * 384;
      gbuf[bb * 388 + rr] = bf2f(src[e]);
    }
    const float* wsrc = W + (long)n * 3072 + k * 1024;
    for (int e = t; e < 1024; e += 256) wbuf[e] = wsrc[e];
    if (k == 0 && t < 32) bbuf[t] = biasN[n * 32 + t];
    __syncthreads();
    const f32x4* gp0 = (const f32x4*)&gbuf[b * 388];
    #pragma unroll 4
    for (int i = 0; i < 32; i++){
      f32x4 g0 = gp0[i * 3 + 0];
      f32x4 g1 = gp0[i * 3 + 1];
      f32x4 g2 = gp0[i * 3 + 2];
      #pragma unroll
      for (int jo = 0; jo < 4; jo++){
        float w = wbuf[i * 32 + oc + jo * 8];   // broadcast within wave
        accv[jo][0] += g0 * w;
        accv[jo][1] += g1 * w;
        accv[jo][2] += g2 * w;
      }
    }
  }
  #pragma unroll
  for (int jo = 0; jo < 4; jo++){
    int o = oc + jo * 8;
    float bv = bbuf[o];
    f32x4 bs = {bv, bv, bv, bv};
    long base = ((long)(b * 32 + o) * 2048 + n) * 12;
    *(f32x4*)(out + base)     = accv[jo][0] + bs;
    *(f32x4*)(out + base + 4) = accv[jo][1] + bs;
    *(f32x4*)(out + base + 8) = accv[jo][2] + bs;
  }
}

extern "C" void kernel_launch(void* const* d_in, const int* in_sizes, int n_in,
                              void* d_out, int out_size, void* d_ws, size_t ws_size,
                              hipStream_t stream){
  const float* x    = (const float*)d_in[0];
  const float* E1   = (const float*)d_in[1];
  const float* E2   = (const float*)d_in[2];
  const float* P1   = (const float*)d_in[3];
  const float* P2   = (const float*)d_in[4];
  const float* BP1  = (const float*)d_in[5];
  const float* BP2  = (const float*)d_in[6];
  const float* fc0w = (const float*)d_in[7];
  const float* fc0b = (const float*)d_in[8];
  const float* fc1w = (const float*)d_in[9];
  const float* fc1b = (const float*)d_in[10];
  const float* fc2w = (const float*)d_in[11];
  const float* fc2b = (const float*)d_in[12];
  float* out = (float*)d_out;

  char* ws = (char*)d_ws;
  size_t off = 0;
  auto carve = [&](size_t bytes) -> char* {
    char* p = ws + off;
    off += (bytes + 255) & ~(size_t)255;
    return p;
  };
  float* h1            = (float*)carve((size_t)65536 * 4);
  float* h2raw         = (float*)carve((size_t)512 * 4);
  float* mmat          = (float*)carve((size_t)256 * 4);
  unsigned short* sup  = (unsigned short*)carve((size_t)2048 * 2048 * 2);
  unsigned short* Xbt  = (unsigned short*)carve((size_t)12288 * 2048 * 2);
  unsigned short* Xb   = (unsigned short*)carve((size_t)2048 * 12288 * 2);
  unsigned short* G1t  = (unsigned short*)carve((size_t)12288 * 2048 * 2);
  unsigned short* G1   = (unsigned short*)carve((size_t)2048 * 12288 * 2);
  float* W             = (float*)carve((size_t)2048 * 3072 * 4);
  float* biasN         = (float*)carve((size_t)2048 * 32 * 4);
  unsigned short* G2   = Xbt;   // alias: Xbt dead after GEMM1, GEMM2 writes G2 here
  (void)ws_size; (void)in_sizes; (void)n_in; (void)out_size;

  k_h1     <<<256, 256, 0, stream>>>(x, fc0w, fc0b, h1);
  k_h2a    <<<512, 256, 0, stream>>>(h1, fc1w, h2raw);
  k_h2b    <<<1, 512, 0, stream>>>(h2raw, fc1b, fc2w, fc2b, mmat);
  k_support<<<2048, 256, 0, stream>>>(E1, E2, mmat, sup);
  k_xb     <<<98304, 256, 0, stream>>>(x, Xb);
  k_xbt    <<<dim3(192, 32), 256, 0, stream>>>(Xb, Xbt);
  k_wb     <<<24832, 256, 0, stream>>>(E1, E2, P1, P2, BP1, BP2, W, biasN);
  k_gemm   <<<dim3(96, 16), 256, 0, stream>>>(sup, Xbt, G1, G1t, 1);   // G1 = S@X
  k_gemm   <<<dim3(96, 16), 256, 0, stream>>>(sup, G1t, G2, G1t, 0);   // G2 = S@G1
  k_final  <<<2048, 256, 0, stream>>>(Xb, G1, G2, W, biasN, out);
}

// Round 3
// 683.301 us; speedup vs baseline: 1.0576x; 1.0576x over previous
//
#include <hip/hip_runtime.h>

// DGCN decomposition:
//   m = MLP(x[0])                       (tiny, fp32)
//   S = softmax(relu(E1 @ m @ E2^T))    (row softmax, fp32 -> bf16)
//   G1 = S @ X, G2 = S @ G1             (bf16 MFMA GEMMs, X = x as [m, (b,i,s)])
//   out[b,o,n,s] = bias[n,o] + sum_{k,i} Gk[n,(b,i,s)] * W[n,k,i,o]
// S^2 is never materialized (saves a 2048^3 GEMM).

typedef float  f32x4  __attribute__((ext_vector_type(4)));
typedef __bf16 bf16x8 __attribute__((ext_vector_type(8)));
typedef unsigned short u16;

#define GLOAD16(gp, lp) __builtin_amdgcn_global_load_lds( \
    (const __attribute__((address_space(1))) void*)(gp),  \
    (__attribute__((address_space(3))) void*)(lp), 16, 0, 0)

__device__ __forceinline__ u16 f2bf(float f){
  union { float f; unsigned u; } v; v.f = f;
  unsigned u = v.u;
  u += 0x7fffu + ((u >> 16) & 1u);   // round-to-nearest-even
  return (u16)(u >> 16);
}
__device__ __forceinline__ float bf2f(u16 h){
  union { unsigned u; float f; } v; v.u = ((unsigned)h) << 16;
  return v.f;
}
// unpack one uint (2 packed bf16) -> float2 {lo, hi} (lo = lower address)
__device__ __forceinline__ float2 unp2(unsigned u){
  union { unsigned q; float f; } a, b;
  a.q = u << 16; b.q = u & 0xffff0000u;
  return make_float2(a.f, b.f);
}

// ---------------- K1: h1[i,n] = tanh(x[0,i,n,:] . fc0_w + fc0_b) ----------------
__global__ void k_h1(const float* __restrict__ x, const float* __restrict__ fc0w,
                     const float* __restrict__ fc0b, float* __restrict__ h1){
  int g = blockIdx.x * 256 + threadIdx.x;        // g = i*2048 + n, 65536 total
  const float* xp = x + (long)g * 12;
  float s = fc0b[0];
  #pragma unroll
  for (int j = 0; j < 12; j++) s += xp[j] * fc0w[j];
  h1[g] = tanhf(s);
}

// ---------------- K2a: h2raw[i*16+d] = sum_n h1[i,n]*fc1_w[d,n] ----------------
__global__ __launch_bounds__(256) void k_h2a(const float* __restrict__ h1,
                                             const float* __restrict__ fc1w,
                                             float* __restrict__ h2raw){
  __shared__ float red[4];
  int id = blockIdx.x;                 // 0..511 = i*16+d
  int i = id >> 4, d = id & 15;
  int t = threadIdx.x;
  const float* hp = h1 + i * 2048;
  const float* wp = fc1w + d * 2048;
  float s = 0.f;
  for (int nn = t; nn < 2048; nn += 256) s += hp[nn] * wp[nn];
  for (int off = 32; off > 0; off >>= 1) s += __shfl_down(s, off, 64);
  if ((t & 63) == 0) red[t >> 6] = s;
  __syncthreads();
  if (t == 0) h2raw[id] = red[0] + red[1] + red[2] + red[3];
}

// ---------------- K2b: h2 = tanh(h2raw + fc1_b); m[d,e] = tanh(sum_i h2[i,d]*fc2_w[e,i] + fc2_b[e]) ----------------
__global__ void k_h2b(const float* __restrict__ h2raw, const float* __restrict__ fc1b,
                      const float* __restrict__ fc2w, const float* __restrict__ fc2b,
                      float* __restrict__ mmat){
  __shared__ float h2[512];
  int t = threadIdx.x;                 // 512 threads
  {
    int d = t & 15;
    h2[t] = tanhf(h2raw[t] + fc1b[d]);
  }
  __syncthreads();
  if (t < 256){
    int dd = t >> 4, e = t & 15;
    float s2 = fc2b[e];
    #pragma unroll
    for (int ii = 0; ii < 32; ii++) s2 += h2[ii * 16 + dd] * fc2w[e * 32 + ii];
    mmat[dd * 16 + e] = tanhf(s2);
  }
}

// ---------------- K3: support row n = softmax_j(relu(sum_d' (E1[n]@m)[d'] * E2[j,d'])) -> bf16 ----------------
__global__ __launch_bounds__(256) void k_support(const float* __restrict__ E1,
                                                 const float* __restrict__ E2,
                                                 const float* __restrict__ mmat,
                                                 u16* __restrict__ sup){
  __shared__ float ml[256];
  __shared__ float tv[16];
  __shared__ float red[8];
  int n = blockIdx.x, t = threadIdx.x;
  ml[t] = mmat[t];
  __syncthreads();
  if (t < 16){
    float s = 0.f;
    const float* er = E1 + n * 16;
    #pragma unroll
    for (int d = 0; d < 16; d++) s += er[d] * ml[d * 16 + t];
    tv[t] = s;
  }
  __syncthreads();
  float lmax = -1e30f;
  float lv[8];
  #pragma unroll
  for (int p = 0; p < 8; p++){
    int j = t + p * 256;
    const float* e2 = E2 + j * 16;
    float s = 0.f;
    #pragma unroll
    for (int d = 0; d < 16; d++) s += tv[d] * e2[d];
    s = fmaxf(s, 0.f);                 // relu BEFORE softmax
    lv[p] = s;
    lmax = fmaxf(lmax, s);
  }
  for (int off = 32; off > 0; off >>= 1) lmax = fmaxf(lmax, __shfl_down(lmax, off, 64));
  if ((t & 63) == 0) red[t >> 6] = lmax;
  __syncthreads();
  if (t == 0) red[0] = fmaxf(fmaxf(red[0], red[1]), fmaxf(red[2], red[3]));
  __syncthreads();
  float mx = red[0];
  float lsum = 0.f;
  #pragma unroll
  for (int p = 0; p < 8; p++){ float e = __expf(lv[p] - mx); lv[p] = e; lsum += e; }
  for (int off = 32; off > 0; off >>= 1) lsum += __shfl_down(lsum, off, 64);
  if ((t & 63) == 0) red[4 + (t >> 6)] = lsum;
  __syncthreads();
  if (t == 0) red[4] = red[4] + red[5] + red[6] + red[7];
  __syncthreads();
  float inv = 1.f / red[4];
  #pragma unroll
  for (int p = 0; p < 8; p++) sup[(long)n * 2048 + t + p * 256] = f2bf(lv[p] * inv);
}

// ---------------- K4a: Xb[m][c] = bf16(x[b,i,m,s]), c=(b*32+i)*12+s ----------------
__global__ void k_xb(const float* __restrict__ x, u16* __restrict__ Xb){
  int idx = blockIdx.x * 256 + threadIdx.x;      // < 2048*12288
  int m = idx / 12288;
  int c = idx - m * 12288;
  int bi = c / 12, s = c - bi * 12;
  Xb[idx] = f2bf(x[((long)bi * 2048 + m) * 12 + s]);
}

// ---------------- K4b: Xbt[c][m] = Xb[m][c]  (64x64 LDS tile transpose) ----------------
__global__ __launch_bounds__(256) void k_xbt(const u16* __restrict__ Xb,
                                             u16* __restrict__ Xbt){
  __shared__ u16 tile[64][65];
  int cT = blockIdx.x * 64;            // 192 tiles over 12288
  int mT = blockIdx.y * 64;            // 32 tiles over 2048
  int t = threadIdx.x;
  int r = t >> 6, cc = t & 63;
  #pragma unroll
  for (int p = 0; p < 16; p++){
    int rr = p * 4 + r;
    tile[rr][cc] = Xb[(long)(mT + rr) * 12288 + cT + cc];
  }
  __syncthreads();
  #pragma unroll
  for (int p = 0; p < 16; p++){
    int rr = p * 4 + r;
    Xbt[(long)(cT + rr) * 2048 + mT + cc] = tile[cc][rr];
  }
}

// ---------------- K6: W[n,k,i,o] = sum_d E1[n,d]P1[d,k,i,o] + E2[n,d]P2[d,k,i,o]; bias likewise ----------------
__global__ void k_wb(const float* __restrict__ E1, const float* __restrict__ E2,
                     const float* __restrict__ P1, const float* __restrict__ P2,
                     const float* __restrict__ BP1, const float* __restrict__ BP2,
                     float* __restrict__ W, float* __restrict__ biasN){
  long g = (long)blockIdx.x * 256 + threadIdx.x;
  const long NW = (long)2048 * 3072;
  if (g < NW){
    int n = (int)(g / 3072), r = (int)(g - (long)n * 3072);
    const float* e1 = E1 + n * 16; const float* e2 = E2 + n * 16;
    float s = 0.f;
    #pragma unroll
    for (int d = 0; d < 16; d++) s += e1[d] * P1[d * 3072 + r] + e2[d] * P2[d * 3072 + r];
    W[g] = s;
  } else {
    long e = g - NW;
    if (e < 2048 * 32){
      int n = (int)(e >> 5), o = (int)(e & 31);
      const float* e1 = E1 + n * 16; const float* e2 = E2 + n * 16;
      float s = 0.f;
      #pragma unroll
      for (int d = 0; d < 16; d++) s += e1[d] * BP1[d * 32 + o] + e2[d] * BP2[d * 32 + o];
      biasN[e] = s;
    }
  }
}

// ---------------- GEMM: C[m][c] = sum_k A[m][k] * Bt[c][k]; optional C^T output ----------------
// m97 structure: 128x128 tile, BK=32, mfma_f32_16x16x32_bf16, global_load_lds width 16.
__global__ __launch_bounds__(256) void k_gemm(const u16* __restrict__ A,
                                              const u16* __restrict__ Bt,
                                              u16* __restrict__ Cd,
                                              u16* __restrict__ Ct,
                                              int writeT){
  __shared__ u16 As[128 * 32];
  __shared__ u16 Bs[128 * 32];
  int tid  = threadIdx.x;
  int wave = tid >> 6, lane = tid & 63;
  int l15 = lane & 15, q = lane >> 4;
  int wm = wave >> 1, wc = wave & 1;
  long mBase = (long)blockIdx.y * 128;
  long cBase = (long)blockIdx.x * 128;
  f32x4 acc[4][4];
  #pragma unroll
  for (int t = 0; t < 4; t++)
    #pragma unroll
    for (int u = 0; u < 4; u++) acc[t][u] = (f32x4){0.f, 0.f, 0.f, 0.f};

  const u16* gA = A  + (mBase + wave * 16 + (lane >> 2)) * 2048 + (lane & 3) * 8;
  const u16* gB = Bt + (cBase + wave * 16 + (lane >> 2)) * 2048 + (lane & 3) * 8;
  u16* lA0 = As + wave * 512;
  u16* lA1 = As + 2048 + wave * 512;
  u16* lB0 = Bs + wave * 512;
  u16* lB1 = Bs + 2048 + wave * 512;

  for (int k0 = 0; k0 < 2048; k0 += 32){
    __syncthreads();
    GLOAD16(gA + k0,              lA0);
    GLOAD16(gA + 64 * 2048 + k0,  lA1);
    GLOAD16(gB + k0,              lB0);
    GLOAD16(gB + 64 * 2048 + k0,  lB1);
    __syncthreads();               // barrier drains vmcnt -> LDS visible
    bf16x8 a[4], b[4];
    #pragma unroll
    for (int t = 0; t < 4; t++)
      a[t] = *(const bf16x8*)&As[(wm * 64 + t * 16 + l15) * 32 + q * 8];
    #pragma unroll
    for (int u = 0; u < 4; u++)
      b[u] = *(const bf16x8*)&Bs[(wc * 64 + u * 16 + l15) * 32 + q * 8];
    #pragma unroll
    for (int t = 0; t < 4; t++)
      #pragma unroll
      for (int u = 0; u < 4; u++)
        acc[t][u] = __builtin_amdgcn_mfma_f32_16x16x32_bf16(a[t], b[u], acc[t][u], 0, 0, 0);
  }
  // epilogue: D lane map col=l15, row=q*4+reg (verified layout)
  #pragma unroll
  for (int t = 0; t < 4; t++){
    int mloc = wm * 64 + t * 16 + q * 4;
    #pragma unroll
    for (int u = 0; u < 4; u++){
      int cloc = wc * 64 + u * 16 + l15;
      long cg = cBase + cloc;
      long mg = mBase + mloc;
      u16 h0 = f2bf(acc[t][u][0]);
      u16 h1v = f2bf(acc[t][u][1]);
      u16 h2v = f2bf(acc[t][u][2]);
      u16 h3v = f2bf(acc[t][u][3]);
      Cd[(mg + 0) * 12288 + cg] = h0;
      Cd[(mg + 1) * 12288 + cg] = h1v;
      Cd[(mg + 2) * 12288 + cg] = h2v;
      Cd[(mg + 3) * 12288 + cg] = h3v;
      if (writeT){
        ushort4 v = make_ushort4(h0, h1v, h2v, h3v);
        *(ushort4*)&Ct[cg * 2048 + mg] = v;
      }
    }
  }
}

// ---------------- K7: out[b,o,n,s] = bias[n,o] + sum_{k,i} Gk[n,(b,i,s)]*W[n,k,i,o] ----------------
// bf16 LDS (25.6KB, 800B/row pad -> 2-way bank alias = free), uint4 16B staging
// loads, in-loop bf16 unpack. ~30KB LDS -> 5 blocks/CU (was 54KB / 2-3).
__global__ __launch_bounds__(256, 4) void k_final(const u16* __restrict__ G0,
                                                  const u16* __restrict__ G1,
                                                  const u16* __restrict__ G2,
                                                  const float* __restrict__ W,
                                                  const float* __restrict__ biasN,
                                                  float* __restrict__ out){
  __shared__ __align__(16) u16 gs[32 * 400];   // per-b row: 384 bf16 + 16 pad
  __shared__ __align__(16) float ws4[1024];    // W[n][k] slice [i=32][o=32]
  __shared__ float bbuf[32];
  int bid = blockIdx.x;
  int n = (bid & 7) * 256 + (bid >> 3);   // XCD-swizzle: adjacent n share an XCD L2
  int t = threadIdx.x;
  int b = t >> 3, oc = t & 7;
  f32x4 acc[4][3];                         // [jo: o=oc+8*jo][s-quad]
  #pragma unroll
  for (int jo = 0; jo < 4; jo++)
    #pragma unroll
    for (int v = 0; v < 3; v++) acc[jo][v] = (f32x4){0.f, 0.f, 0.f, 0.f};

  const u16* srcs[3] = {G0, G1, G2};
  for (int k = 0; k < 3; k++){
    __syncthreads();
    // stage G[n] slab: 12288 bf16 = 1536 x 16B chunks; 48 chunks per b-row
    const uint4* src = (const uint4*)(srcs[k] + (long)n * 12288);
    #pragma unroll
    for (int p = 0; p < 6; p++){
      int c = t + p * 256;
      int br = c / 48, wi = c - br * 48;
      *(uint4*)&gs[br * 400 + wi * 8] = src[c];
    }
    const float4* wsrc = (const float4*)(W + (long)n * 3072 + k * 1024);
    *(float4*)&ws4[t * 4] = wsrc[t];
    if (k == 0 && t < 8) *(float4*)&bbuf[t * 4] = ((const float4*)(biasN + (long)n * 32))[t];
    __syncthreads();

    const u16* gp = gs + b * 400;
    #pragma unroll 4
    for (int ii = 0; ii < 16; ii++){       // two i per iter: i0=2ii, i1=2ii+1
      uint4 A  = *(const uint4*)&gp[ii * 24];
      uint4 Bc = *(const uint4*)&gp[ii * 24 + 8];
      uint4 Cc = *(const uint4*)&gp[ii * 24 + 16];
      float2 p0 = unp2(A.x),  p1 = unp2(A.y),  p2 = unp2(A.z),  p3 = unp2(A.w);
      float2 p4 = unp2(Bc.x), p5 = unp2(Bc.y), p6 = unp2(Bc.z), p7 = unp2(Bc.w);
      float2 p8 = unp2(Cc.x), p9 = unp2(Cc.y), pa = unp2(Cc.z), pb = unp2(Cc.w);
      f32x4 G0v0 = (f32x4){p0.x, p0.y, p1.x, p1.y};
      f32x4 G0v1 = (f32x4){p2.x, p2.y, p3.x, p3.y};
      f32x4 G0v2 = (f32x4){p4.x, p4.y, p5.x, p5.y};
      f32x4 G1v0 = (f32x4){p6.x, p6.y, p7.x, p7.y};
      f32x4 G1v1 = (f32x4){p8.x, p8.y, p9.x, p9.y};
      f32x4 G1v2 = (f32x4){pa.x, pa.y, pb.x, pb.y};
      #pragma unroll
      for (int jo = 0; jo < 4; jo++){
        float w0 = ws4[(ii * 2)     * 32 + oc + jo * 8];   // broadcast reads
        float w1 = ws4[(ii * 2 + 1) * 32 + oc + jo * 8];
        acc[jo][0] += G0v0 * w0;
        acc[jo][1] += G0v1 * w0;
        acc[jo][2] += G0v2 * w0;
        acc[jo][0] += G1v0 * w1;
        acc[jo][1] += G1v1 * w1;
        acc[jo][2] += G1v2 * w1;
      }
    }
  }
  #pragma unroll
  for (int jo = 0; jo < 4; jo++){
    int o = oc + jo * 8;
    float bv = bbuf[o];
    f32x4 bs = {bv, bv, bv, bv};
    long base = ((long)(b * 32 + o) * 2048 + n) * 12;
    *(f32x4*)(out + base)     = acc[jo][0] + bs;
    *(f32x4*)(out + base + 4) = acc[jo][1] + bs;
    *(f32x4*)(out + base + 8) = acc[jo][2] + bs;
  }
}

extern "C" void kernel_launch(void* const* d_in, const int* in_sizes, int n_in,
                              void* d_out, int out_size, void* d_ws, size_t ws_size,
                              hipStream_t stream){
  const float* x    = (const float*)d_in[0];
  const float* E1   = (const float*)d_in[1];
  const float* E2   = (const float*)d_in[2];
  const float* P1   = (const float*)d_in[3];
  const float* P2   = (const float*)d_in[4];
  const float* BP1  = (const float*)d_in[5];
  const float* BP2  = (const float*)d_in[6];
  const float* fc0w = (const float*)d_in[7];
  const float* fc0b = (const float*)d_in[8];
  const float* fc1w = (const float*)d_in[9];
  const float* fc1b = (const float*)d_in[10];
  const float* fc2w = (const float*)d_in[11];
  const float* fc2b = (const float*)d_in[12];
  float* out = (float*)d_out;

  char* ws = (char*)d_ws;
  size_t off = 0;
  auto carve = [&](size_t bytes) -> char* {
    char* p = ws + off;
    off += (bytes + 255) & ~(size_t)255;
    return p;
  };
  float* h1            = (float*)carve((size_t)65536 * 4);
  float* h2raw         = (float*)carve((size_t)512 * 4);
  float* mmat          = (float*)carve((size_t)256 * 4);
  u16* sup             = (u16*)carve((size_t)2048 * 2048 * 2);
  u16* Xbt             = (u16*)carve((size_t)12288 * 2048 * 2);
  u16* Xb              = (u16*)carve((size_t)2048 * 12288 * 2);
  u16* G1t             = (u16*)carve((size_t)12288 * 2048 * 2);
  u16* G1              = (u16*)carve((size_t)2048 * 12288 * 2);
  float* W             = (float*)carve((size_t)2048 * 3072 * 4);
  float* biasN         = (float*)carve((size_t)2048 * 32 * 4);
  u16* G2              = Xbt;   // alias: Xbt dead after GEMM1, GEMM2 writes G2 here
  (void)ws_size; (void)in_sizes; (void)n_in; (void)out_size;

  k_h1     <<<256, 256, 0, stream>>>(x, fc0w, fc0b, h1);
  k_h2a    <<<512, 256, 0, stream>>>(h1, fc1w, h2raw);
  k_h2b    <<<1, 512, 0, stream>>>(h2raw, fc1b, fc2w, fc2b, mmat);
  k_support<<<2048, 256, 0, stream>>>(E1, E2, mmat, sup);
  k_xb     <<<98304, 256, 0, stream>>>(x, Xb);
  k_xbt    <<<dim3(192, 32), 256, 0, stream>>>(Xb, Xbt);
  k_wb     <<<24832, 256, 0, stream>>>(E1, E2, P1, P2, BP1, BP2, W, biasN);
  k_gemm   <<<dim3(96, 16), 256, 0, stream>>>(sup, Xbt, G1, G1t, 1);   // G1 = S@X
  k_gemm   <<<dim3(96, 16), 256, 0, stream>>>(sup, G1t, G2, G1t, 0);   // G2 = S@G1
  k_final  <<<2048, 256, 0, stream>>>(Xb, G1, G2, W, biasN, out);
}

// Round 4
// 663.613 us; speedup vs baseline: 1.0890x; 1.0297x over previous
//
#include <hip/hip_runtime.h>

// DGCN decomposition:
//   m = MLP(x[0])                       (tiny, fp32)
//   S = softmax(relu(E1 @ m @ E2^T))    (row softmax, fp32 -> bf16)
//   G1 = S @ X, G2 = S @ G1             (bf16 MFMA GEMMs, X = x as [m, (b,i,s)])
//   out[b,o,n,s] = bias[n,o] + sum_{k,i} Gk[n,(b,i,s)] * W[n,k,i,o]
// S^2 is never materialized (saves a 2048^3 GEMM).

typedef float  f32x4  __attribute__((ext_vector_type(4)));
typedef __bf16 bf16x8 __attribute__((ext_vector_type(8)));
typedef unsigned short u16;

#define GLOAD16(gp, lp) __builtin_amdgcn_global_load_lds( \
    (const __attribute__((address_space(1))) void*)(gp),  \
    (__attribute__((address_space(3))) void*)(lp), 16, 0, 0)

__device__ __forceinline__ u16 f2bf(float f){
  union { float f; unsigned u; } v; v.f = f;
  unsigned u = v.u;
  u += 0x7fffu + ((u >> 16) & 1u);   // round-to-nearest-even
  return (u16)(u >> 16);
}
__device__ __forceinline__ float bf2f(u16 h){
  union { unsigned u; float f; } v; v.u = ((unsigned)h) << 16;
  return v.f;
}
// unpack one uint (2 packed bf16) -> float2 {lo, hi} (lo = lower address)
__device__ __forceinline__ float2 unp2(unsigned u){
  union { unsigned q; float f; } a, b;
  a.q = u << 16; b.q = u & 0xffff0000u;
  return make_float2(a.f, b.f);
}

// ---------------- K1: h1[i,n] = tanh(x[0,i,n,:] . fc0_w + fc0_b) ----------------
__global__ void k_h1(const float* __restrict__ x, const float* __restrict__ fc0w,
                     const float* __restrict__ fc0b, float* __restrict__ h1){
  int g = blockIdx.x * 256 + threadIdx.x;        // g = i*2048 + n, 65536 total
  const float* xp = x + (long)g * 12;
  float s = fc0b[0];
  #pragma unroll
  for (int j = 0; j < 12; j++) s += xp[j] * fc0w[j];
  h1[g] = tanhf(s);
}

// ---------------- K2a: h2raw[i*16+d] = sum_n h1[i,n]*fc1_w[d,n] ----------------
__global__ __launch_bounds__(256) void k_h2a(const float* __restrict__ h1,
                                             const float* __restrict__ fc1w,
                                             float* __restrict__ h2raw){
  __shared__ float red[4];
  int id = blockIdx.x;                 // 0..511 = i*16+d
  int i = id >> 4, d = id & 15;
  int t = threadIdx.x;
  const float* hp = h1 + i * 2048;
  const float* wp = fc1w + d * 2048;
  float s = 0.f;
  for (int nn = t; nn < 2048; nn += 256) s += hp[nn] * wp[nn];
  for (int off = 32; off > 0; off >>= 1) s += __shfl_down(s, off, 64);
  if ((t & 63) == 0) red[t >> 6] = s;
  __syncthreads();
  if (t == 0) h2raw[id] = red[0] + red[1] + red[2] + red[3];
}

// ---------------- K2b: h2 = tanh(h2raw + fc1_b); m[d,e] = tanh(sum_i h2[i,d]*fc2_w[e,i] + fc2_b[e]) ----------------
__global__ void k_h2b(const float* __restrict__ h2raw, const float* __restrict__ fc1b,
                      const float* __restrict__ fc2w, const float* __restrict__ fc2b,
                      float* __restrict__ mmat){
  __shared__ float h2[512];
  int t = threadIdx.x;                 // 512 threads
  {
    int d = t & 15;
    h2[t] = tanhf(h2raw[t] + fc1b[d]);
  }
  __syncthreads();
  if (t < 256){
    int dd = t >> 4, e = t & 15;
    float s2 = fc2b[e];
    #pragma unroll
    for (int ii = 0; ii < 32; ii++) s2 += h2[ii * 16 + dd] * fc2w[e * 32 + ii];
    mmat[dd * 16 + e] = tanhf(s2);
  }
}

// ---------------- K3: support row n = softmax_j(relu(sum_d' (E1[n]@m)[d'] * E2[j,d'])) -> bf16 ----------------
__global__ __launch_bounds__(256) void k_support(const float* __restrict__ E1,
                                                 const float* __restrict__ E2,
                                                 const float* __restrict__ mmat,
                                                 u16* __restrict__ sup){
  __shared__ float ml[256];
  __shared__ float tv[16];
  __shared__ float red[8];
  int n = blockIdx.x, t = threadIdx.x;
  ml[t] = mmat[t];
  __syncthreads();
  if (t < 16){
    float s = 0.f;
    const float* er = E1 + n * 16;
    #pragma unroll
    for (int d = 0; d < 16; d++) s += er[d] * ml[d * 16 + t];
    tv[t] = s;
  }
  __syncthreads();
  float lmax = -1e30f;
  float lv[8];
  #pragma unroll
  for (int p = 0; p < 8; p++){
    int j = t + p * 256;
    const float* e2 = E2 + j * 16;
    float s = 0.f;
    #pragma unroll
    for (int d = 0; d < 16; d++) s += tv[d] * e2[d];
    s = fmaxf(s, 0.f);                 // relu BEFORE softmax
    lv[p] = s;
    lmax = fmaxf(lmax, s);
  }
  for (int off = 32; off > 0; off >>= 1) lmax = fmaxf(lmax, __shfl_down(lmax, off, 64));
  if ((t & 63) == 0) red[t >> 6] = lmax;
  __syncthreads();
  if (t == 0) red[0] = fmaxf(fmaxf(red[0], red[1]), fmaxf(red[2], red[3]));
  __syncthreads();
  float mx = red[0];
  float lsum = 0.f;
  #pragma unroll
  for (int p = 0; p < 8; p++){ float e = __expf(lv[p] - mx); lv[p] = e; lsum += e; }
  for (int off = 32; off > 0; off >>= 1) lsum += __shfl_down(lsum, off, 64);
  if ((t & 63) == 0) red[4 + (t >> 6)] = lsum;
  __syncthreads();
  if (t == 0) red[4] = red[4] + red[5] + red[6] + red[7];
  __syncthreads();
  float inv = 1.f / red[4];
  #pragma unroll
  for (int p = 0; p < 8; p++) sup[(long)n * 2048 + t + p * 256] = f2bf(lv[p] * inv);
}

// ---------------- K4a: Xb[m][c] = bf16(x[b,i,m,s]), c=(b*32+i)*12+s ----------------
__global__ void k_xb(const float* __restrict__ x, u16* __restrict__ Xb){
  int idx = blockIdx.x * 256 + threadIdx.x;      // < 2048*12288
  int m = idx / 12288;
  int c = idx - m * 12288;
  int bi = c / 12, s = c - bi * 12;
  Xb[idx] = f2bf(x[((long)bi * 2048 + m) * 12 + s]);
}

// ---------------- K4b: Xbt[c][m] = Xb[m][c]  (64x64 LDS tile transpose) ----------------
__global__ __launch_bounds__(256) void k_xbt(const u16* __restrict__ Xb,
                                             u16* __restrict__ Xbt){
  __shared__ u16 tile[64][65];
  int cT = blockIdx.x * 64;            // 192 tiles over 12288
  int mT = blockIdx.y * 64;            // 32 tiles over 2048
  int t = threadIdx.x;
  int r = t >> 6, cc = t & 63;
  #pragma unroll
  for (int p = 0; p < 16; p++){
    int rr = p * 4 + r;
    tile[rr][cc] = Xb[(long)(mT + rr) * 12288 + cT + cc];
  }
  __syncthreads();
  #pragma unroll
  for (int p = 0; p < 16; p++){
    int rr = p * 4 + r;
    Xbt[(long)(cT + rr) * 2048 + mT + cc] = tile[cc][rr];
  }
}

// ---------------- K6: W[n,k,i,o] = sum_d E1[n,d]P1[d,k,i,o] + E2[n,d]P2[d,k,i,o]; bias likewise ----------------
__global__ void k_wb(const float* __restrict__ E1, const float* __restrict__ E2,
                     const float* __restrict__ P1, const float* __restrict__ P2,
                     const float* __restrict__ BP1, const float* __restrict__ BP2,
                     float* __restrict__ W, float* __restrict__ biasN){
  long g = (long)blockIdx.x * 256 + threadIdx.x;
  const long NW = (long)2048 * 3072;
  if (g < NW){
    int n = (int)(g / 3072), r = (int)(g - (long)n * 3072);
    const float* e1 = E1 + n * 16; const float* e2 = E2 + n * 16;
    float s = 0.f;
    #pragma unroll
    for (int d = 0; d < 16; d++) s += e1[d] * P1[d * 3072 + r] + e2[d] * P2[d * 3072 + r];
    W[g] = s;
  } else {
    long e = g - NW;
    if (e < 2048 * 32){
      int n = (int)(e >> 5), o = (int)(e & 31);
      const float* e1 = E1 + n * 16; const float* e2 = E2 + n * 16;
      float s = 0.f;
      #pragma unroll
      for (int d = 0; d < 16; d++) s += e1[d] * BP1[d * 32 + o] + e2[d] * BP2[d * 32 + o];
      biasN[e] = s;
    }
  }
}

// ---------------- GEMM: C[m][c] = sum_k A[m][k] * Bt[c][k]; optional C^T output ----------------
// m97 structure + R3 changes:
//   * double-buffered BK=32x2: 8 global_load_lds per barrier pair (half the barriers)
//   * LDS-staged epilogue: transposed C-tile in LDS (ds_write_b64 from MFMA D-layout),
//     then coalesced 256B-row stores for Ct and column-gather+pack dwordx4 for Cd
//   * XCD swizzle: 12 temporally-adjacent blocks per XCD share the sup A-tile
__global__ __launch_bounds__(256) void k_gemm(const u16* __restrict__ A,
                                              const u16* __restrict__ Bt,
                                              u16* __restrict__ Cd,
                                              u16* __restrict__ Ct,
                                              int writeT){
  __shared__ u16 lds[128 * 136];   // staging uses [0,16384); epilogue uses 128x136
  // staging offsets (u16 elems): As0=0, As1=4096, Bs0=8192, Bs1=12288
  int tid  = threadIdx.x;
  int wave = tid >> 6, lane = tid & 63;
  int l15 = lane & 15, q = lane >> 4;
  int wm = wave >> 1, wc = wave & 1;

  // XCD swizzle: dispatch ordinal lin; xcd = lin&7; per-XCD sequential slots share yN
  int lin  = blockIdx.y * 96 + blockIdx.x;
  int xcd  = lin & 7;
  int slot = lin >> 3;                // 0..191
  int yN   = slot / 12;               // 0..15  (m-tile)
  int xN   = (slot - yN * 12) * 8 + xcd;   // 0..95 (c-tile)
  long mBase = (long)yN * 128;
  long cBase = (long)xN * 128;

  f32x4 acc[4][4];
  #pragma unroll
  for (int t = 0; t < 4; t++)
    #pragma unroll
    for (int u = 0; u < 4; u++) acc[t][u] = (f32x4){0.f, 0.f, 0.f, 0.f};

  // staging map: lane -> row = wave*16 + lane/4, 16B chunk = (lane&3)*8 elems;
  // lds dest = wave-uniform base + lane*16B (global_load_lds constraint).
  const u16* gA = A  + (mBase + wave * 16 + (lane >> 2)) * 2048 + (lane & 3) * 8;
  const u16* gB = Bt + (cBase + wave * 16 + (lane >> 2)) * 2048 + (lane & 3) * 8;
  u16* lA = lds + wave * 512;          // As0 rows 0..63
  u16* lB = lds + 8192 + wave * 512;   // Bs0 rows 0..63

  for (int k0 = 0; k0 < 2048; k0 += 64){
    __syncthreads();
    GLOAD16(gA + k0,                  lA);          // As0 rows 0-63
    GLOAD16(gA + 64 * 2048 + k0,      lA + 2048);   // As0 rows 64-127
    GLOAD16(gA + k0 + 32,             lA + 4096);   // As1 rows 0-63
    GLOAD16(gA + 64 * 2048 + k0 + 32, lA + 6144);   // As1 rows 64-127
    GLOAD16(gB + k0,                  lB);          // Bs0
    GLOAD16(gB + 64 * 2048 + k0,      lB + 2048);
    GLOAD16(gB + k0 + 32,             lB + 4096);   // Bs1
    GLOAD16(gB + 64 * 2048 + k0 + 32, lB + 6144);
    __syncthreads();               // barrier drains vmcnt -> LDS visible
    bf16x8 a[4], b[4];
    // half 0 (k0..k0+31)
    #pragma unroll
    for (int t = 0; t < 4; t++)
      a[t] = *(const bf16x8*)&lds[(wm * 64 + t * 16 + l15) * 32 + q * 8];
    #pragma unroll
    for (int u = 0; u < 4; u++)
      b[u] = *(const bf16x8*)&lds[8192 + (wc * 64 + u * 16 + l15) * 32 + q * 8];
    #pragma unroll
    for (int t = 0; t < 4; t++)
      #pragma unroll
      for (int u = 0; u < 4; u++)
        acc[t][u] = __builtin_amdgcn_mfma_f32_16x16x32_bf16(a[t], b[u], acc[t][u], 0, 0, 0);
    // half 1 (k0+32..k0+63)
    #pragma unroll
    for (int t = 0; t < 4; t++)
      a[t] = *(const bf16x8*)&lds[4096 + (wm * 64 + t * 16 + l15) * 32 + q * 8];
    #pragma unroll
    for (int u = 0; u < 4; u++)
      b[u] = *(const bf16x8*)&lds[12288 + (wc * 64 + u * 16 + l15) * 32 + q * 8];
    #pragma unroll
    for (int t = 0; t < 4; t++)
      #pragma unroll
      for (int u = 0; u < 4; u++)
        acc[t][u] = __builtin_amdgcn_mfma_f32_16x16x32_bf16(a[t], b[u], acc[t][u], 0, 0, 0);
  }

  // ---- epilogue: build transposed tile tileT[c][m] (stride 136) in LDS ----
  // D lane map: col(c)=l15, row(m)=q*4+reg -> 4 consecutive m per lane = 1 ds_write_b64
  __syncthreads();   // all LDS staging reads done before overwrite
  #pragma unroll
  for (int t = 0; t < 4; t++){
    int mloc = wm * 64 + t * 16 + q * 4;
    #pragma unroll
    for (int u = 0; u < 4; u++){
      int cloc = wc * 64 + u * 16 + l15;
      ushort4 v = make_ushort4(f2bf(acc[t][u][0]), f2bf(acc[t][u][1]),
                               f2bf(acc[t][u][2]), f2bf(acc[t][u][3]));
      *(ushort4*)&lds[cloc * 136 + mloc] = v;
    }
  }
  __syncthreads();
  int rr = tid >> 4;          // 0..15
  int ch = (tid & 15) * 8;    // 8-elem chunk
  if (writeT){
    // Ct rows are c: 128 m-elems contiguous -> 16 threads x 16B = 256B coalesced
    #pragma unroll
    for (int p = 0; p < 8; p++){
      int r = p * 16 + rr;
      uint4 v = *(const uint4*)&lds[r * 136 + ch];
      *(uint4*)&Ct[(cBase + r) * 2048 + mBase + ch] = v;
    }
  }
  // Cd rows are m: gather a column-run from tileT, pack, coalesced dwordx4
  #pragma unroll
  for (int p = 0; p < 8; p++){
    int m = p * 16 + rr;
    unsigned w0 = (unsigned)lds[(ch + 0) * 136 + m] | ((unsigned)lds[(ch + 1) * 136 + m] << 16);
    unsigned w1 = (unsigned)lds[(ch + 2) * 136 + m] | ((unsigned)lds[(ch + 3) * 136 + m] << 16);
    unsigned w2 = (unsigned)lds[(ch + 4) * 136 + m] | ((unsigned)lds[(ch + 5) * 136 + m] << 16);
    unsigned w3 = (unsigned)lds[(ch + 6) * 136 + m] | ((unsigned)lds[(ch + 7) * 136 + m] << 16);
    uint4 v = make_uint4(w0, w1, w2, w3);
    *(uint4*)&Cd[(mBase + m) * 12288 + cBase + ch] = v;
  }
}

// ---------------- K7: out[b,o,n,s] = bias[n,o] + sum_{k,i} Gk[n,(b,i,s)]*W[n,k,i,o] ----------------
// bf16 LDS (25.6KB, 800B/row pad -> 2-way bank alias = free), uint4 16B staging
// loads, in-loop bf16 unpack. ~30KB LDS -> 5 blocks/CU.
__global__ __launch_bounds__(256, 4) void k_final(const u16* __restrict__ G0,
                                                  const u16* __restrict__ G1,
                                                  const u16* __restrict__ G2,
                                                  const float* __restrict__ W,
                                                  const float* __restrict__ biasN,
                                                  float* __restrict__ out){
  __shared__ __align__(16) u16 gs[32 * 400];   // per-b row: 384 bf16 + 16 pad
  __shared__ __align__(16) float ws4[1024];    // W[n][k] slice [i=32][o=32]
  __shared__ float bbuf[32];
  int bid = blockIdx.x;
  int n = (bid & 7) * 256 + (bid >> 3);   // XCD-swizzle: adjacent n share an XCD L2
  int t = threadIdx.x;
  int b = t >> 3, oc = t & 7;
  f32x4 acc[4][3];                         // [jo: o=oc+8*jo][s-quad]
  #pragma unroll
  for (int jo = 0; jo < 4; jo++)
    #pragma unroll
    for (int v = 0; v < 3; v++) acc[jo][v] = (f32x4){0.f, 0.f, 0.f, 0.f};

  const u16* srcs[3] = {G0, G1, G2};
  for (int k = 0; k < 3; k++){
    __syncthreads();
    // stage G[n] slab: 12288 bf16 = 1536 x 16B chunks; 48 chunks per b-row
    const uint4* src = (const uint4*)(srcs[k] + (long)n * 12288);
    #pragma unroll
    for (int p = 0; p < 6; p++){
      int c = t + p * 256;
      int br = c / 48, wi = c - br * 48;
      *(uint4*)&gs[br * 400 + wi * 8] = src[c];
    }
    const float4* wsrc = (const float4*)(W + (long)n * 3072 + k * 1024);
    *(float4*)&ws4[t * 4] = wsrc[t];
    if (k == 0 && t < 8) *(float4*)&bbuf[t * 4] = ((const float4*)(biasN + (long)n * 32))[t];
    __syncthreads();

    const u16* gp = gs + b * 400;
    #pragma unroll 4
    for (int ii = 0; ii < 16; ii++){       // two i per iter: i0=2ii, i1=2ii+1
      uint4 A  = *(const uint4*)&gp[ii * 24];
      uint4 Bc = *(const uint4*)&gp[ii * 24 + 8];
      uint4 Cc = *(const uint4*)&gp[ii * 24 + 16];
      float2 p0 = unp2(A.x),  p1 = unp2(A.y),  p2 = unp2(A.z),  p3 = unp2(A.w);
      float2 p4 = unp2(Bc.x), p5 = unp2(Bc.y), p6 = unp2(Bc.z), p7 = unp2(Bc.w);
      float2 p8 = unp2(Cc.x), p9 = unp2(Cc.y), pa = unp2(Cc.z), pb = unp2(Cc.w);
      f32x4 G0v0 = (f32x4){p0.x, p0.y, p1.x, p1.y};
      f32x4 G0v1 = (f32x4){p2.x, p2.y, p3.x, p3.y};
      f32x4 G0v2 = (f32x4){p4.x, p4.y, p5.x, p5.y};
      f32x4 G1v0 = (f32x4){p6.x, p6.y, p7.x, p7.y};
      f32x4 G1v1 = (f32x4){p8.x, p8.y, p9.x, p9.y};
      f32x4 G1v2 = (f32x4){pa.x, pa.y, pb.x, pb.y};
      #pragma unroll
      for (int jo = 0; jo < 4; jo++){
        float w0 = ws4[(ii * 2)     * 32 + oc + jo * 8];   // broadcast reads
        float w1 = ws4[(ii * 2 + 1) * 32 + oc + jo * 8];
        acc[jo][0] += G0v0 * w0;
        acc[jo][1] += G0v1 * w0;
        acc[jo][2] += G0v2 * w0;
        acc[jo][0] += G1v0 * w1;
        acc[jo][1] += G1v1 * w1;
        acc[jo][2] += G1v2 * w1;
      }
    }
  }
  #pragma unroll
  for (int jo = 0; jo < 4; jo++){
    int o = oc + jo * 8;
    float bv = bbuf[o];
    f32x4 bs = {bv, bv, bv, bv};
    long base = ((long)(b * 32 + o) * 2048 + n) * 12;
    *(f32x4*)(out + base)     = acc[jo][0] + bs;
    *(f32x4*)(out + base + 4) = acc[jo][1] + bs;
    *(f32x4*)(out + base + 8) = acc[jo][2] + bs;
  }
}

extern "C" void kernel_launch(void* const* d_in, const int* in_sizes, int n_in,
                              void* d_out, int out_size, void* d_ws, size_t ws_size,
                              hipStream_t stream){
  const float* x    = (const float*)d_in[0];
  const float* E1   = (const float*)d_in[1];
  const float* E2   = (const float*)d_in[2];
  const float* P1   = (const float*)d_in[3];
  const float* P2   = (const float*)d_in[4];
  const float* BP1  = (const float*)d_in[5];
  const float* BP2  = (const float*)d_in[6];
  const float* fc0w = (const float*)d_in[7];
  const float* fc0b = (const float*)d_in[8];
  const float* fc1w = (const float*)d_in[9];
  const float* fc1b = (const float*)d_in[10];
  const float* fc2w = (const float*)d_in[11];
  const float* fc2b = (const float*)d_in[12];
  float* out = (float*)d_out;

  char* ws = (char*)d_ws;
  size_t off = 0;
  auto carve = [&](size_t bytes) -> char* {
    char* p = ws + off;
    off += (bytes + 255) & ~(size_t)255;
    return p;
  };
  float* h1            = (float*)carve((size_t)65536 * 4);
  float* h2raw         = (float*)carve((size_t)512 * 4);
  float* mmat          = (float*)carve((size_t)256 * 4);
  u16* sup             = (u16*)carve((size_t)2048 * 2048 * 2);
  u16* Xbt             = (u16*)carve((size_t)12288 * 2048 * 2);
  u16* Xb              = (u16*)carve((size_t)2048 * 12288 * 2);
  u16* G1t             = (u16*)carve((size_t)12288 * 2048 * 2);
  u16* G1              = (u16*)carve((size_t)2048 * 12288 * 2);
  float* W             = (float*)carve((size_t)2048 * 3072 * 4);
  float* biasN         = (float*)carve((size_t)2048 * 32 * 4);
  u16* G2              = Xbt;   // alias: Xbt dead after GEMM1, GEMM2 writes G2 here
  (void)ws_size; (void)in_sizes; (void)n_in; (void)out_size;

  k_h1     <<<256, 256, 0, stream>>>(x, fc0w, fc0b, h1);
  k_h2a    <<<512, 256, 0, stream>>>(h1, fc1w, h2raw);
  k_h2b    <<<1, 512, 0, stream>>>(h2raw, fc1b, fc2w, fc2b, mmat);
  k_support<<<2048, 256, 0, stream>>>(E1, E2, mmat, sup);
  k_xb     <<<98304, 256, 0, stream>>>(x, Xb);
  k_xbt    <<<dim3(192, 32), 256, 0, stream>>>(Xb, Xbt);
  k_wb     <<<24832, 256, 0, stream>>>(E1, E2, P1, P2, BP1, BP2, W, biasN);
  k_gemm   <<<dim3(96, 16), 256, 0, stream>>>(sup, Xbt, G1, G1t, 1);   // G1 = S@X
  k_gemm   <<<dim3(96, 16), 256, 0, stream>>>(sup, G1t, G2, G1t, 0);   // G2 = S@G1
  k_final  <<<2048, 256, 0, stream>>>(Xb, G1, G2, W, biasN, out);
}